// Round 7
// baseline (25.892 us; speedup 1.0000x reference)
//
#include <hip/hip_runtime.h>
#include <hip/hip_fp16.h>

// y[b,q] = sum_{d,f} amp[b,d,f] * sin(x_q[b,q,d] * freq[b,d,f])
//
// R7: coalescing fix. R3/R5/R6 all plateaued ~25us because every structure
// gave one 256B q-row per thread -> wave loads at stride 256B = 64 lines per
// load instr (8x transaction inflation). Now a wave covers 4 q-rows with
// lanes CONTIGUOUS within each 128B half-row; per-q reduction via shfl_xor.
//
//  K1 (build): for each (b,d): 512-pt table of g(x)=sum_f amp*sin(freq*x)
//     over [-8,8] via Chebyshev recurrence (R5/R6-validated, absmax 0.5).
//     Entry i packs half2(g_i, g_{i+1}-g_i) -> lookup = 1 ds_read_b32 + fma.
//  K2 (lookup): block=(b, 32-d half, 512 q's), 512 thr, 64KB LDS table ->
//     2 blocks/CU, 4 waves/SIMD. Lane l: q=q0+(l>>4), d-pair=(l&15)*2.
//     Reduce 16 lanes (shfl_xor 1,2,4,8), atomicAdd into zeroed out.
#define ND 64
#define NF 16
#define TPTS 512
#define SEGP 16
#define DELTA 0.03125f
#define XSCALE 32.0f
#define XBIAS 256.0f   // (x+8)*32
#define IMAX 510.99f   // i+1 <= 511
#define DSL 32
#define QSL 512

// ---------------- K1: build packed (value,slope) tables ----------------
__global__ __launch_bounds__(256) void sinreg_build(
    const float* __restrict__ z, unsigned* __restrict__ tblg, int B) {
  const int t = blockIdx.x * 256 + threadIdx.x;   // (b, d, seg)
  const int b   = t >> 11;
  const int d   = (t >> 5) & (ND - 1);
  const int seg = t & 31;
  const int k0  = seg * SEGP;
  const float xs = -8.0f + k0 * DELTA;

  const float* __restrict__ zb = z + (size_t)b * (2 * ND * NF);
  const float* __restrict__ ap = zb + d * NF;            // amp[d][f]
  const float* __restrict__ fp = zb + ND * NF + d * NF;  // freq[d][f]
  constexpr float INV2PI = 0.15915494309189535f;

  float g[SEGP + 1];  // one extra point for the last slope
  #pragma unroll
  for (int k = 0; k <= SEGP; ++k) g[k] = 0.f;

  #pragma unroll
  for (int f = 0; f < NF; ++f) {
    const float fv = fp[f], av = ap[f];
    float s0 = __builtin_amdgcn_sinf(__builtin_amdgcn_fractf(fv * xs * INV2PI));
    float s1 = __builtin_amdgcn_sinf(
        __builtin_amdgcn_fractf(fv * (xs + DELTA) * INV2PI));
    const float th2 = (fv * DELTA) * (fv * DELTA);
    const float w = fmaf(th2, fmaf(th2, 0.0833333333f, -1.0f), 2.0f);  // 2cos
    g[0] = fmaf(av, s0, g[0]);
    g[1] = fmaf(av, s1, g[1]);
    #pragma unroll
    for (int k = 2; k <= SEGP; ++k) {
      const float s2 = fmaf(w, s1, -s0);  // s_{k+1} = w*s_k - s_{k-1}
      g[k] = fmaf(av, s2, g[k]);
      s0 = s1; s1 = s2;
    }
  }

  unsigned pk[SEGP];
  #pragma unroll
  for (int k = 0; k < SEGP; ++k) {
    __half2 h;
    h.x = __float2half(g[k]);
    h.y = __float2half(g[k + 1] - g[k]);
    pk[k] = *reinterpret_cast<unsigned*>(&h);
  }
  uint4* __restrict__ dst =
      reinterpret_cast<uint4*>(tblg + ((size_t)(b * ND + d) * TPTS) + k0);
  #pragma unroll
  for (int j = 0; j < 4; ++j)
    dst[j] = make_uint4(pk[4 * j], pk[4 * j + 1], pk[4 * j + 2], pk[4 * j + 3]);
}

// ---------------- K2: coalesced lookup ----------------
__global__ __launch_bounds__(512, 4) void sinreg_lookup(
    const unsigned* __restrict__ tblg,
    const float* __restrict__ xq,
    float* __restrict__ out,
    int B, int Q) {
  __shared__ unsigned s_tbl[DSL * TPTS];  // 64 KB

  const int b   = blockIdx.y;
  const int dsl = blockIdx.x & 1;   // which 32-d half
  const int qsl = blockIdx.x >> 1;  // which 512-q slice
  const int tid = threadIdx.x;

  // stage packed table (64 KB), coalesced uint4
  {
    const uint4* __restrict__ src =
        reinterpret_cast<const uint4*>(tblg + (size_t)(b * ND + dsl * DSL) * TPTS);
    uint4* __restrict__ dst = reinterpret_cast<uint4*>(s_tbl);
    #pragma unroll
    for (int i = 0; i < 8; ++i) dst[tid + i * 512] = src[tid + i * 512];
  }
  __syncthreads();

  const int lane = tid & 63;
  const int wv   = tid >> 6;           // 0..7
  const int qsub = lane >> 4;          // 0..3 : q within the wave's 4-row group
  const int dp   = (lane & 15) * 2;    // local d pair (0..30)

  // rows of the two tables this lane uses (base bank = dp*512 % 32 = 0 -> i%32)
  const unsigned* __restrict__ trow0 = &s_tbl[dp * TPTS];
  const unsigned* __restrict__ trow1 = trow0 + TPTS;

  const int qw0 = qsl * QSL + wv * 64;  // wave's first q (64 q's, 16 iters x 4)
  // lane-contiguous: 16 lanes cover one 128B half-row
  const float* __restrict__ xbase =
      xq + ((size_t)b * Q + qw0 + qsub) * ND + dsl * DSL + dp;

  #pragma unroll 4
  for (int it = 0; it < 16; ++it) {
    const float2 x2 = *reinterpret_cast<const float2*>(xbase + (size_t)it * 4 * ND);

    float r;
    {
      float tt = fmaf(x2.x, XSCALE, XBIAS);
      tt = fminf(fmaxf(tt, 0.0f), IMAX);
      const unsigned i = (unsigned)tt;
      const float u = tt - (float)i;
      const unsigned pv = trow0[i];
      const float2 gs = __half22float2(*reinterpret_cast<const __half2*>(&pv));
      r = fmaf(gs.y, u, gs.x);
    }
    {
      float tt = fmaf(x2.y, XSCALE, XBIAS);
      tt = fminf(fmaxf(tt, 0.0f), IMAX);
      const unsigned i = (unsigned)tt;
      const float u = tt - (float)i;
      const unsigned pv = trow1[i];
      const float2 gs = __half22float2(*reinterpret_cast<const __half2*>(&pv));
      r = fmaf(gs.y, u, gs.x + r);
    }
    // sum the 16 lanes holding this q's 32 d-contributions
    r += __shfl_xor(r, 1);
    r += __shfl_xor(r, 2);
    r += __shfl_xor(r, 4);
    r += __shfl_xor(r, 8);
    if ((lane & 15) == 0)
      atomicAdd(&out[(size_t)b * Q + qw0 + it * 4 + qsub], r);
  }
}

// ---------------- fallback (direct v_sin, R3-validated) ----------------
__global__ __launch_bounds__(256, 4) void sinreg_direct(
    const float* __restrict__ z, const float* __restrict__ xq,
    float* __restrict__ out, int B, int Q) {
  __shared__ float s_part[4][64];
  const int b = blockIdx.y;
  const int lane = threadIdx.x & 63;
  const int wv = __builtin_amdgcn_readfirstlane((int)(threadIdx.x >> 6));
  const int q = blockIdx.x * 64 + lane;
  const float* __restrict__ zb  = z + (size_t)b * (2 * ND * NF);
  const float* __restrict__ amp = zb + (16 * wv) * NF;
  const float* __restrict__ frq = zb + ND * NF + (16 * wv) * NF;
  const float4* __restrict__ xrow =
      reinterpret_cast<const float4*>(xq + ((size_t)b * Q + q) * ND + 16 * wv);
  float4 xv0 = xrow[0], xv1 = xrow[1], xv2 = xrow[2], xv3 = xrow[3];
  constexpr float INV2PI = 0.15915494309189535f;
  const float xs[16] = {
      xv0.x * INV2PI, xv0.y * INV2PI, xv0.z * INV2PI, xv0.w * INV2PI,
      xv1.x * INV2PI, xv1.y * INV2PI, xv1.z * INV2PI, xv1.w * INV2PI,
      xv2.x * INV2PI, xv2.y * INV2PI, xv2.z * INV2PI, xv2.w * INV2PI,
      xv3.x * INV2PI, xv3.y * INV2PI, xv3.z * INV2PI, xv3.w * INV2PI};
  float acc0 = 0.f, acc1 = 0.f, acc2 = 0.f, acc3 = 0.f;
  #pragma unroll
  for (int dd = 0; dd < 16; ++dd) {
    const float xsd = xs[dd];
    #pragma unroll
    for (int f = 0; f < NF; f += 4) {
      acc0 = fmaf(__builtin_amdgcn_sinf(__builtin_amdgcn_fractf(xsd * frq[dd * NF + f + 0])), amp[dd * NF + f + 0], acc0);
      acc1 = fmaf(__builtin_amdgcn_sinf(__builtin_amdgcn_fractf(xsd * frq[dd * NF + f + 1])), amp[dd * NF + f + 1], acc1);
      acc2 = fmaf(__builtin_amdgcn_sinf(__builtin_amdgcn_fractf(xsd * frq[dd * NF + f + 2])), amp[dd * NF + f + 2], acc2);
      acc3 = fmaf(__builtin_amdgcn_sinf(__builtin_amdgcn_fractf(xsd * frq[dd * NF + f + 3])), amp[dd * NF + f + 3], acc3);
    }
  }
  s_part[wv][lane] = (acc0 + acc1) + (acc2 + acc3);
  __syncthreads();
  if (threadIdx.x < 64) {
    float r = (s_part[0][lane] + s_part[1][lane]) + (s_part[2][lane] + s_part[3][lane]);
    out[(size_t)b * Q + (size_t)blockIdx.x * 64 + lane] = r;
  }
}

extern "C" void kernel_launch(void* const* d_in, const int* in_sizes, int n_in,
                              void* d_out, int out_size, void* d_ws, size_t ws_size,
                              hipStream_t stream) {
  const float* z  = (const float*)d_in[0];
  const float* xq = (const float*)d_in[1];
  float* out = (float*)d_out;

  const int B = in_sizes[0] / (2 * ND * NF);  // 32
  const int Q = in_sizes[1] / (B * ND);       // 4096

  const size_t tbl_bytes = (size_t)B * ND * TPTS * sizeof(unsigned);  // 4 MB
  if (ws_size < tbl_bytes) {  // fallback: direct evaluation (R3, validated)
    dim3 grid(Q / 64, B);
    sinreg_direct<<<grid, 256, 0, stream>>>(z, xq, out, B, Q);
    return;
  }

  unsigned* tblg = (unsigned*)d_ws;

  // K1: build all (b,d) tables once. threads = B*ND*32 = 65536
  sinreg_build<<<dim3((B * ND * 32) / 256), 256, 0, stream>>>(z, tblg, B);

  // two d-half blocks accumulate via atomicAdd -> zero out first
  hipMemsetAsync(d_out, 0, (size_t)out_size * sizeof(float), stream);

  // K2: (2 dhalf x 8 qsl) x B = 512 blocks, 512 thr, 64KB LDS
  dim3 grid(2 * (Q / QSL), B);
  sinreg_lookup<<<grid, 512, 0, stream>>>(tblg, xq, out, B, Q);
}

// Round 8
// 25.221 us; speedup vs baseline: 1.0266x; 1.0266x over previous
//
#include <hip/hip_runtime.h>
#include <hip/hip_fp16.h>

// y[b,q] = sum_{d,f} amp[b,d,f] * sin(x_q[b,q,d] * freq[b,d,f])
//
// R8: two dispatches, zero atomics, zero memset.
//  K1 (build): per (b,d) 512-pt table of g(x)=sum_f amp*sin(freq*x) over
//     [-8,8], Chebyshev recurrence, entries packed half2(value, slope)
//     -> one ds_read_b32 + fma per lookup. (R5-R7 validated, absmax 0.5.)
//  K2 (lookup): block = (b, 256-q slice), 512 thr, 64 KB LDS -> 2 blocks/CU.
//     Stage half-table d0..31 from ws, pass 0 (per-q partials in registers,
//     16-lane shfl reduce), restage d32..63, pass 1, plain coalesced store.
//     Lane l: q-sub = l>>4, d-pair = (l&15)*2 -> x-loads lane-contiguous.
#define ND 64
#define NF 16
#define TPTS 512
#define SEGP 16
#define DELTA 0.03125f
#define XSCALE 32.0f
#define XBIAS 256.0f   // (x+8)*32
#define IMAX 510.99f   // i+1 <= 511
#define QSL 256        // q's per lookup block

// ---------------- K1: build packed (value,slope) tables ----------------
__global__ __launch_bounds__(256) void sinreg_build(
    const float* __restrict__ z, unsigned* __restrict__ tblg, int B) {
  const int t = blockIdx.x * 256 + threadIdx.x;   // (b, d, seg)
  const int b   = t >> 11;
  const int d   = (t >> 5) & (ND - 1);
  const int seg = t & 31;
  const int k0  = seg * SEGP;
  const float xs = -8.0f + k0 * DELTA;

  const float* __restrict__ zb = z + (size_t)b * (2 * ND * NF);
  const float* __restrict__ ap = zb + d * NF;            // amp[d][f]
  const float* __restrict__ fp = zb + ND * NF + d * NF;  // freq[d][f]
  constexpr float INV2PI = 0.15915494309189535f;

  float g[SEGP + 1];  // one extra point for the last slope
  #pragma unroll
  for (int k = 0; k <= SEGP; ++k) g[k] = 0.f;

  #pragma unroll
  for (int f = 0; f < NF; ++f) {
    const float fv = fp[f], av = ap[f];
    float s0 = __builtin_amdgcn_sinf(__builtin_amdgcn_fractf(fv * xs * INV2PI));
    float s1 = __builtin_amdgcn_sinf(
        __builtin_amdgcn_fractf(fv * (xs + DELTA) * INV2PI));
    const float th2 = (fv * DELTA) * (fv * DELTA);
    const float w = fmaf(th2, fmaf(th2, 0.0833333333f, -1.0f), 2.0f);  // 2cos
    g[0] = fmaf(av, s0, g[0]);
    g[1] = fmaf(av, s1, g[1]);
    #pragma unroll
    for (int k = 2; k <= SEGP; ++k) {
      const float s2 = fmaf(w, s1, -s0);  // s_{k+1} = w*s_k - s_{k-1}
      g[k] = fmaf(av, s2, g[k]);
      s0 = s1; s1 = s2;
    }
  }

  unsigned pk[SEGP];
  #pragma unroll
  for (int k = 0; k < SEGP; ++k) {
    __half2 h;
    h.x = __float2half(g[k]);
    h.y = __float2half(g[k + 1] - g[k]);
    pk[k] = *reinterpret_cast<unsigned*>(&h);
  }
  uint4* __restrict__ dst =
      reinterpret_cast<uint4*>(tblg + ((size_t)(b * ND + d) * TPTS) + k0);
  #pragma unroll
  for (int j = 0; j < 4; ++j)
    dst[j] = make_uint4(pk[4 * j], pk[4 * j + 1], pk[4 * j + 2], pk[4 * j + 3]);
}

// ---------------- K2: two-pass lookup, register partials ----------------
__global__ __launch_bounds__(512, 4) void sinreg_lookup(
    const unsigned* __restrict__ tblg,
    const float* __restrict__ xq,
    float* __restrict__ out,
    int B, int Q) {
  __shared__ unsigned s_tbl[32 * TPTS];  // 64 KB: one 32-d half-table

  const int b   = blockIdx.y;
  const int qsl = blockIdx.x;
  const int tid = threadIdx.x;
  const int lane = tid & 63;
  const int wv   = tid >> 6;          // 0..7
  const int qsub = lane >> 4;         // 0..3
  const int dp   = (lane & 15) * 2;   // local d pair within the staged half

  const int q0 = qsl * QSL + wv * 32; // this wave's 32 q's (8 iters x 4)
  const unsigned* __restrict__ trow0 = &s_tbl[dp * TPTS];
  const unsigned* __restrict__ trow1 = trow0 + TPTS;

  float acc[8];

#define STAGE(H)                                                               \
  {                                                                            \
    const uint4* __restrict__ src = reinterpret_cast<const uint4*>(            \
        tblg + (size_t)(b * ND + (H) * 32) * TPTS);                            \
    uint4* __restrict__ dst = reinterpret_cast<uint4*>(s_tbl);                 \
    _Pragma("unroll")                                                          \
    for (int i = 0; i < 8; ++i) dst[tid + i * 512] = src[tid + i * 512];       \
  }

#define LOOKUP2(R, XPTR)                                                       \
  {                                                                            \
    const float2 x2 = *reinterpret_cast<const float2*>(XPTR);                  \
    float tt = fmaf(x2.x, XSCALE, XBIAS);                                      \
    tt = fminf(fmaxf(tt, 0.0f), IMAX);                                         \
    unsigned i = (unsigned)tt;                                                 \
    float u = tt - (float)i;                                                   \
    unsigned pv = trow0[i];                                                    \
    float2 gs = __half22float2(*reinterpret_cast<const __half2*>(&pv));        \
    R = fmaf(gs.y, u, gs.x);                                                   \
    tt = fmaf(x2.y, XSCALE, XBIAS);                                            \
    tt = fminf(fmaxf(tt, 0.0f), IMAX);                                         \
    i = (unsigned)tt;                                                          \
    u = tt - (float)i;                                                         \
    pv = trow1[i];                                                             \
    gs = __half22float2(*reinterpret_cast<const __half2*>(&pv));               \
    R = fmaf(gs.y, u, gs.x + R);                                               \
    R += __shfl_xor(R, 1);                                                     \
    R += __shfl_xor(R, 2);                                                     \
    R += __shfl_xor(R, 4);                                                     \
    R += __shfl_xor(R, 8);                                                     \
  }

  // ---- pass 0: d 0..31 ----
  STAGE(0);
  __syncthreads();
  {
    const float* __restrict__ xp =
        xq + ((size_t)b * Q + q0 + qsub) * ND + dp;  // half 0 cols
    #pragma unroll
    for (int it = 0; it < 8; ++it) {
      float r;
      LOOKUP2(r, xp + (size_t)it * 4 * ND);
      acc[it] = r;
    }
  }
  __syncthreads();  // all reads of s_tbl done before restage

  // ---- pass 1: d 32..63 ----
  STAGE(1);
  __syncthreads();
  {
    const float* __restrict__ xp =
        xq + ((size_t)b * Q + q0 + qsub) * ND + 32 + dp;  // half 1 cols
    #pragma unroll
    for (int it = 0; it < 8; ++it) {
      float r;
      LOOKUP2(r, xp + (size_t)it * 4 * ND);
      if ((lane & 15) == 0)
        out[(size_t)b * Q + q0 + it * 4 + qsub] = acc[it] + r;
    }
  }
#undef STAGE
#undef LOOKUP2
}

// ---------------- fallback (direct v_sin, R3-validated) ----------------
__global__ __launch_bounds__(256, 4) void sinreg_direct(
    const float* __restrict__ z, const float* __restrict__ xq,
    float* __restrict__ out, int B, int Q) {
  __shared__ float s_part[4][64];
  const int b = blockIdx.y;
  const int lane = threadIdx.x & 63;
  const int wv = __builtin_amdgcn_readfirstlane((int)(threadIdx.x >> 6));
  const int q = blockIdx.x * 64 + lane;
  const float* __restrict__ zb  = z + (size_t)b * (2 * ND * NF);
  const float* __restrict__ amp = zb + (16 * wv) * NF;
  const float* __restrict__ frq = zb + ND * NF + (16 * wv) * NF;
  const float4* __restrict__ xrow =
      reinterpret_cast<const float4*>(xq + ((size_t)b * Q + q) * ND + 16 * wv);
  float4 xv0 = xrow[0], xv1 = xrow[1], xv2 = xrow[2], xv3 = xrow[3];
  constexpr float INV2PI = 0.15915494309189535f;
  const float xs[16] = {
      xv0.x * INV2PI, xv0.y * INV2PI, xv0.z * INV2PI, xv0.w * INV2PI,
      xv1.x * INV2PI, xv1.y * INV2PI, xv1.z * INV2PI, xv1.w * INV2PI,
      xv2.x * INV2PI, xv2.y * INV2PI, xv2.z * INV2PI, xv2.w * INV2PI,
      xv3.x * INV2PI, xv3.y * INV2PI, xv3.z * INV2PI, xv3.w * INV2PI};
  float acc0 = 0.f, acc1 = 0.f, acc2 = 0.f, acc3 = 0.f;
  #pragma unroll
  for (int dd = 0; dd < 16; ++dd) {
    const float xsd = xs[dd];
    #pragma unroll
    for (int f = 0; f < NF; f += 4) {
      acc0 = fmaf(__builtin_amdgcn_sinf(__builtin_amdgcn_fractf(xsd * frq[dd * NF + f + 0])), amp[dd * NF + f + 0], acc0);
      acc1 = fmaf(__builtin_amdgcn_sinf(__builtin_amdgcn_fractf(xsd * frq[dd * NF + f + 1])), amp[dd * NF + f + 1], acc1);
      acc2 = fmaf(__builtin_amdgcn_sinf(__builtin_amdgcn_fractf(xsd * frq[dd * NF + f + 2])), amp[dd * NF + f + 2], acc2);
      acc3 = fmaf(__builtin_amdgcn_sinf(__builtin_amdgcn_fractf(xsd * frq[dd * NF + f + 3])), amp[dd * NF + f + 3], acc3);
    }
  }
  s_part[wv][lane] = (acc0 + acc1) + (acc2 + acc3);
  __syncthreads();
  if (threadIdx.x < 64) {
    float r = (s_part[0][lane] + s_part[1][lane]) + (s_part[2][lane] + s_part[3][lane]);
    out[(size_t)b * Q + (size_t)blockIdx.x * 64 + lane] = r;
  }
}

extern "C" void kernel_launch(void* const* d_in, const int* in_sizes, int n_in,
                              void* d_out, int out_size, void* d_ws, size_t ws_size,
                              hipStream_t stream) {
  const float* z  = (const float*)d_in[0];
  const float* xq = (const float*)d_in[1];
  float* out = (float*)d_out;

  const int B = in_sizes[0] / (2 * ND * NF);  // 32
  const int Q = in_sizes[1] / (B * ND);       // 4096

  const size_t tbl_bytes = (size_t)B * ND * TPTS * sizeof(unsigned);  // 4 MB
  if (ws_size < tbl_bytes) {  // fallback: direct evaluation (R3, validated)
    dim3 grid(Q / 64, B);
    sinreg_direct<<<grid, 256, 0, stream>>>(z, xq, out, B, Q);
    return;
  }

  unsigned* tblg = (unsigned*)d_ws;

  // K1: build all (b,d) tables once. threads = B*ND*32 = 65536
  sinreg_build<<<dim3((B * ND * 32) / 256), 256, 0, stream>>>(z, tblg, B);

  // K2: (Q/QSL) x B = 512 blocks, 512 thr, 64 KB LDS, no atomics/memset
  dim3 grid(Q / QSL, B);
  sinreg_lookup<<<grid, 512, 0, stream>>>(tblg, xq, out, B, Q);
}